// Round 2
// 94.109 us; speedup vs baseline: 1.0578x; 1.0578x over previous
//
#include <hip/hip_runtime.h>
#include <hip/hip_fp16.h>

// Problem constants (from reference)
#define N_VISITS  16384
#define MAX_CODES 64
#define DIM       64
#define NUM_CODES 100000

// Native vector type usable with __builtin_nontemporal_* (HIP's float4 is a
// class and is rejected by the builtin).
typedef float f32x4 __attribute__((ext_vector_type(4)));

// ---------------------------------------------------------------------------
// Kernel 1: convert emb table fp32 -> fp16 into workspace (12.8 MB).
// Re-run every launch (workspace is poisoned between iterations).
// Streaming, HBM-bound: 25.6 MB read + 12.8 MB write ~= 6 us.
// Non-temporal reads (fp32 table not reused); normal stores so the fp16
// table lands in L2/L3 warm for the gather kernel.
// ---------------------------------------------------------------------------
__global__ __launch_bounds__(256) void emb_to_half_kernel(
    const float* __restrict__ emb, __half* __restrict__ embh)
{
    const size_t n8 = (size_t)NUM_CODES * DIM / 8;   // 800000 groups of 8 elems
    size_t i = (size_t)blockIdx.x * blockDim.x + threadIdx.x;
    const size_t stride = (size_t)gridDim.x * blockDim.x;
    for (; i < n8; i += stride) {
        const f32x4* src = (const f32x4*)emb + 2 * i;
        f32x4 a = __builtin_nontemporal_load(src);
        f32x4 b = __builtin_nontemporal_load(src + 1);
        union { __half2 h[4]; f32x4 f; } u;
        u.h[0] = __floats2half2_rn(a.x, a.y);
        u.h[1] = __floats2half2_rn(a.z, a.w);
        u.h[2] = __floats2half2_rn(b.x, b.y);
        u.h[3] = __floats2half2_rn(b.z, b.w);
        ((f32x4*)embh)[i] = u.f;   // 16B store, keep cached
    }
}

// ---------------------------------------------------------------------------
// Kernel 2: one wave per visit, fp16 table.
// Row = 128 B. Lane decomposition: r = lane>>3 (8 row-slots), t = lane&7
// (which 16B chunk of the 128B row). One wave-wide float4 gather covers
// 8 table rows (1 KB). 8 such gathers cover the visit's 64 rows; all are
// issued before any accumulation.
// ---------------------------------------------------------------------------
__global__ __launch_bounds__(256) void visit_mean_kernel(
    const int* __restrict__ code_ids,
    const __half* __restrict__ embh,
    float* __restrict__ out)
{
    const int wave_in_block = threadIdx.x >> 6;
    const int lane = threadIdx.x & 63;
    const int visit = blockIdx.x * 4 + wave_in_block;

    const int r = lane >> 3;   // which of 8 rows this lane reads per gather
    const int t = lane & 7;    // which 16B chunk (8 fp16 = 8 dims) of the row

    // lane j holds id j of this visit (one coalesced 256B load per wave).
    // Non-temporal: ids are streamed once, keep them out of L2.
    const int my_id = __builtin_nontemporal_load(
        code_ids + (size_t)visit * MAX_CODES + lane);
    const unsigned long long valid = __ballot(my_id >= 0);
    const int count = __popcll(valid);

    // Phase 1: broadcast the ids each lane needs: id[8*j + r], j=0..7
    int ids[8];
    #pragma unroll
    for (int j = 0; j < 8; ++j) {
        ids[j] = __shfl(my_id, 8 * j + r, 64);
    }

    // Phase 2: issue all 8 16B gathers (8 rows / 1 KB per wave instruction)
    f32x4 v[8];
    #pragma unroll
    for (int j = 0; j < 8; ++j) {
        const int id   = ids[j];
        const int safe = (id >= 0) ? id : 0;
        v[j] = *((const f32x4*)(embh + (size_t)safe * DIM) + t);
    }

    // Phase 3: masked accumulate in fp32. Lane covers dims t*8 .. t*8+7.
    float acc[8] = {0.f, 0.f, 0.f, 0.f, 0.f, 0.f, 0.f, 0.f};
    #pragma unroll
    for (int j = 0; j < 8; ++j) {
        const float m = (ids[j] >= 0) ? 1.0f : 0.0f;
        const __half2* h = (const __half2*)&v[j];
        #pragma unroll
        for (int k = 0; k < 4; ++k) {
            const float2 f = __half22float2(h[k]);
            acc[2 * k]     = fmaf(m, f.x, acc[2 * k]);
            acc[2 * k + 1] = fmaf(m, f.y, acc[2 * k + 1]);
        }
    }

    // Reduce the 8 row-slots (lanes with equal t) via xor-butterfly on
    // lane bits 3,4,5.
    #pragma unroll
    for (int k = 0; k < 8; ++k) acc[k] += __shfl_xor(acc[k], 8, 64);
    #pragma unroll
    for (int k = 0; k < 8; ++k) acc[k] += __shfl_xor(acc[k], 16, 64);
    #pragma unroll
    for (int k = 0; k < 8; ++k) acc[k] += __shfl_xor(acc[k], 32, 64);

    // Lanes 0..7 each own dims t*8 .. t*8+7: two 16B stores each
    // (wave-wide: 2 store instructions x 128 B).
    if (lane < 8) {
        const float scale = (count > 0) ? (1.0f / (float)count) : 0.0f;
        f32x4 o0, o1;
        o0.x = acc[0] * scale; o0.y = acc[1] * scale;
        o0.z = acc[2] * scale; o0.w = acc[3] * scale;
        o1.x = acc[4] * scale; o1.y = acc[5] * scale;
        o1.z = acc[6] * scale; o1.w = acc[7] * scale;
        f32x4* dst = (f32x4*)(out + (size_t)visit * DIM + lane * 8);
        __builtin_nontemporal_store(o0, dst);
        __builtin_nontemporal_store(o1, dst + 1);
    }
}

extern "C" void kernel_launch(void* const* d_in, const int* in_sizes, int n_in,
                              void* d_out, int out_size, void* d_ws, size_t ws_size,
                              hipStream_t stream) {
    const int*   code_ids = (const int*)d_in[0];    // [N_VISITS, MAX_CODES] int32
    const float* emb      = (const float*)d_in[1];  // [NUM_CODES, DIM] fp32
    float*       out      = (float*)d_out;          // [N_VISITS, DIM] fp32
    __half*      embh     = (__half*)d_ws;          // 12.8 MB fp16 table

    // Kernel 1: fp32 -> fp16 table conversion (must precede gather; same stream)
    emb_to_half_kernel<<<2048, 256, 0, stream>>>(emb, embh);

    // Kernel 2: gather + masked mean, one wave per visit
    const int waves_per_block = 4;                  // 256 threads
    const int grid = N_VISITS / waves_per_block;    // 4096 blocks
    visit_mean_kernel<<<grid, 256, 0, stream>>>(code_ids, embh, out);
}